// Round 5
// baseline (288.653 us; speedup 1.0000x reference)
//
#include <hip/hip_runtime.h>

// GraphConv: out[t] += input[s] * (esgn*enorm), 3.2M edges, 100K nodes, D=32 fp32.
// Round 16: partition was 96us with everything idle (VALU 2.3%, HBM 9%, occ 15%,
// 1.44M LDS conflicts) -- 63KB LDS capped it at 2 blocks/CU and it ran two LDS
// atomic passes + an 8-round scan + serial copy-out. Since record order WITHIN
// a bucket is irrelevant to bucket_accum, the histogram atomicAdd return value
// IS the rank: new partition keeps rank[j] in registers (unrolled, static idx),
// reserves per-bucket global space directly from lh[] (no scan, no srec, no
// copy-out), and scatters straight to global recs. LDS 63KB -> 8KB.
// Pipeline: bhist -> bscan -> partition -> bucket_accum (R15, verified).

#define NB   256
#define KMAX 1024         // max buckets (span 128 -> n_nodes <= 131072)
#define SPAN_SHIFT 7
#define SPAN 128
#define PT   5888         // partition tile edges (=256*23)
#define PTC  (PT / NB)    // 23 edges per thread
#define CAP  6144         // bucket_accum LDS record capacity (48KB)

// Bucket-level histogram: LDS counters, one global atomic per bucket/block.
__global__ __launch_bounds__(NB) void bhist_kernel(
    const int* __restrict__ tidx, int* __restrict__ bcnt, int n_edges)
{
    __shared__ int lh[KMAX];
    for (int i = threadIdx.x; i < KMAX; i += NB) lh[i] = 0;
    __syncthreads();
    int stride = gridDim.x * NB;
    for (int e = blockIdx.x * NB + threadIdx.x; e < n_edges; e += stride)
        atomicAdd(&lh[tidx[e] >> SPAN_SHIFT], 1);
    __syncthreads();
    for (int i = threadIdx.x; i < KMAX; i += NB)
        if (lh[i]) atomicAdd(&bcnt[i], lh[i]);
}

// Exclusive scan over K (<=1024) bucket counts -> bbase[0..K].
__global__ __launch_bounds__(1024) void bscan_kernel(
    const int* __restrict__ bcnt, int* __restrict__ bbase, int K)
{
    __shared__ int part[KMAX];
    int t = threadIdx.x;
    int c = (t < K) ? bcnt[t] : 0;
    part[t] = c;
    __syncthreads();
    for (int off = 1; off < KMAX; off <<= 1) {
        int v = (t >= off) ? part[t - off] : 0;
        __syncthreads();
        part[t] += v;
        __syncthreads();
    }
    if (t < K) bbase[t] = part[t] - c;
    if (t == K - 1) bbase[K] = part[t];
}

// Partition R16: rank-from-histogram, direct global scatter. LDS = 8KB.
//   pass 1: rank[j] = atomicAdd(&lh[b], 1)   (register array, fully unrolled)
//   reserve: gb[b] = bbase[b] + atomicAdd(&bcur0[b], lh[b])
//   pass 2: recs[gb[b] + rank[j]] = {rec, w}  (tidx re-read is L1-hot)
__global__ __launch_bounds__(NB) void partition_kernel(
    const int* __restrict__ sidx, const int* __restrict__ tidx,
    const float* __restrict__ enorm, const float* __restrict__ esgn,
    const int* __restrict__ bbase, int* __restrict__ bcur0,
    int2* __restrict__ recs, int n_edges)
{
    __shared__ int lh[KMAX];               // 4 KB
    __shared__ int gb[KMAX];               // 4 KB
    int t = threadIdx.x;
    for (int i = t; i < KMAX; i += NB) lh[i] = 0;
    __syncthreads();

    size_t tb = (size_t)blockIdx.x * PT;
    int rank[PTC];
    #pragma unroll
    for (int j = 0; j < PTC; ++j) {
        int e = (int)tb + j * NB + t;
        if (e < n_edges)
            rank[j] = atomicAdd(&lh[tidx[e] >> SPAN_SHIFT], 1);
    }
    __syncthreads();
    // per-bucket global reservation: thread t owns buckets [4t, 4t+4)
    int b0 = t << 2;
    #pragma unroll
    for (int q = 0; q < 4; ++q) {
        int b = b0 + q;
        int c = lh[b];
        if (c > 0) gb[b] = bbase[b] + atomicAdd(&bcur0[b], c);
    }
    __syncthreads();
    #pragma unroll
    for (int j = 0; j < PTC; ++j) {
        int e = (int)tb + j * NB + t;
        if (e < n_edges) {
            int tn = tidx[e];
            int b = tn >> SPAN_SHIFT;
            unsigned rec = ((unsigned)sidx[e] << SPAN_SHIFT) | (unsigned)(tn & (SPAN - 1));
            float w = enorm[e] * esgn[e];
            recs[gb[b] + rank[j]] = make_int2((int)rec, __float_as_int(w));
        }
    }
}

// Fused node-sort + accumulate, one block per bucket (128 nodes).
// Normal path: bucket records staged & node-sorted entirely in LDS, then
// 8 lanes/node x float4 accumulate with 4-deep unroll (no atomics).
// Overflow path (cnt > CAP, adversarial only): atomic accumulate.
__global__ __launch_bounds__(1024) void bucket_accum(
    const float* __restrict__ input, const int2* __restrict__ recs,
    const int* __restrict__ bbase, float* __restrict__ out, int n_nodes)
{
    __shared__ int2 srec[CAP];             // 48 KB
    __shared__ int lcnt[SPAN];
    __shared__ int lbeg[SPAN];
    __shared__ int lcur[SPAN];
    int b = blockIdx.x;
    int t = threadIdx.x;
    int bstart = bbase[b], bend = bbase[b + 1];
    int base_node = b << SPAN_SHIFT;

    if (bend - bstart <= CAP) {
        if (t < SPAN) lcnt[t] = 0;
        __syncthreads();
        // node histogram
        for (int i = bstart + t; i < bend; i += 1024)
            atomicAdd(&lcnt[recs[i].x & (SPAN - 1)], 1);
        __syncthreads();
        // exclusive scan over SPAN=128 (masked H-S, uniform barriers)
        int c = (t < SPAN) ? lcnt[t] : 0;
        if (t < SPAN) lbeg[t] = c;
        __syncthreads();
        for (int off = 1; off < SPAN; off <<= 1) {
            int v = (t < SPAN && t >= off) ? lbeg[t - off] : 0;
            __syncthreads();
            if (t < SPAN) lbeg[t] += v;
            __syncthreads();
        }
        if (t < SPAN) {
            int excl = lbeg[t] - c;
            lbeg[t] = excl;
            lcur[t] = excl;
        }
        __syncthreads();
        // scatter into LDS, node-sorted
        for (int i = bstart + t; i < bend; i += 1024) {
            int2 r = recs[i];
            int pos = atomicAdd(&lcur[r.x & (SPAN - 1)], 1);
            srec[pos] = r;
        }
        __syncthreads();
        // accumulate: 8 lanes per node, float4 per lane, 4-deep unroll
        int node = t >> 3;
        int lane = t & 7;
        int beg = lbeg[node];
        int end = beg + lcnt[node];
        float4 acc = make_float4(0.f, 0.f, 0.f, 0.f);
        int i = beg;
        for (; i + 3 < end; i += 4) {
            int2 r0 = srec[i];
            int2 r1 = srec[i + 1];
            int2 r2 = srec[i + 2];
            int2 r3 = srec[i + 3];
            float4 v0 = ((const float4*)(input + (size_t)(((unsigned)r0.x) >> SPAN_SHIFT) * 32))[lane];
            float4 v1 = ((const float4*)(input + (size_t)(((unsigned)r1.x) >> SPAN_SHIFT) * 32))[lane];
            float4 v2 = ((const float4*)(input + (size_t)(((unsigned)r2.x) >> SPAN_SHIFT) * 32))[lane];
            float4 v3 = ((const float4*)(input + (size_t)(((unsigned)r3.x) >> SPAN_SHIFT) * 32))[lane];
            float w0 = __int_as_float(r0.y);
            float w1 = __int_as_float(r1.y);
            float w2 = __int_as_float(r2.y);
            float w3 = __int_as_float(r3.y);
            acc.x = fmaf(w0, v0.x, acc.x);
            acc.y = fmaf(w0, v0.y, acc.y);
            acc.z = fmaf(w0, v0.z, acc.z);
            acc.w = fmaf(w0, v0.w, acc.w);
            acc.x = fmaf(w1, v1.x, acc.x);
            acc.y = fmaf(w1, v1.y, acc.y);
            acc.z = fmaf(w1, v1.z, acc.z);
            acc.w = fmaf(w1, v1.w, acc.w);
            acc.x = fmaf(w2, v2.x, acc.x);
            acc.y = fmaf(w2, v2.y, acc.y);
            acc.z = fmaf(w2, v2.z, acc.z);
            acc.w = fmaf(w2, v2.w, acc.w);
            acc.x = fmaf(w3, v3.x, acc.x);
            acc.y = fmaf(w3, v3.y, acc.y);
            acc.z = fmaf(w3, v3.z, acc.z);
            acc.w = fmaf(w3, v3.w, acc.w);
        }
        for (; i < end; ++i) {
            int2 r = srec[i];
            float w = __int_as_float(r.y);
            float4 v = ((const float4*)(input + (size_t)(((unsigned)r.x) >> SPAN_SHIFT) * 32))[lane];
            acc.x = fmaf(w, v.x, acc.x);
            acc.y = fmaf(w, v.y, acc.y);
            acc.z = fmaf(w, v.z, acc.z);
            acc.w = fmaf(w, v.w, acc.w);
        }
        int gnode = base_node + node;
        if (gnode < n_nodes)
            ((float4*)(out + (size_t)gnode * 32))[lane] = acc;
    } else {
        // overflow fallback (correctness only; ~never taken on random data)
        for (int i = t; i < SPAN * 32; i += 1024) {
            int gn = base_node + (i >> 5);
            if (gn < n_nodes) out[(size_t)gn * 32 + (i & 31)] = 0.f;
        }
        __syncthreads();
        for (int i = bstart + t; i < bend; i += 1024) {
            int2 r = recs[i];
            float w = __int_as_float(r.y);
            int s = (int)(((unsigned)r.x) >> SPAN_SHIFT);
            int gn = base_node + (r.x & (SPAN - 1));
            if (gn < n_nodes)
                for (int j = 0; j < 32; ++j)
                    atomicAdd(&out[(size_t)gn * 32 + j], w * input[(size_t)s * 32 + j]);
        }
    }
}

// Last-resort fallback (R3): direct atomic scatter.
__global__ __launch_bounds__(NB) void graphconv_scatter(
    const float* __restrict__ input, const int* __restrict__ sidx,
    const int* __restrict__ tidx, const float* __restrict__ enorm,
    const float* __restrict__ esgn, float* __restrict__ out, int n_edges)
{
    int t = blockIdx.x * NB + threadIdx.x;
    int e = t >> 3;
    int sub = t & 7;
    if (e >= n_edges) return;
    int s = sidx[e];
    int d = tidx[e];
    float w = enorm[e] * esgn[e];
    const float4* src = (const float4*)(input + (size_t)s * 32);
    float4 v = src[sub];
    float* op = out + (size_t)d * 32 + sub * 4;
    atomicAdd(op + 0, v.x * w);
    atomicAdd(op + 1, v.y * w);
    atomicAdd(op + 2, v.z * w);
    atomicAdd(op + 3, v.w * w);
}

extern "C" void kernel_launch(void* const* d_in, const int* in_sizes, int n_in,
                              void* d_out, int out_size, void* d_ws, size_t ws_size,
                              hipStream_t stream) {
    const float* input = (const float*)d_in[0];
    const int*   eidx  = (const int*)d_in[1];   // int64 in reference -> int32 here
    const float* enorm = (const float*)d_in[2];
    const float* esgn  = (const float*)d_in[3];
    float*       out   = (float*)d_out;

    int n_edges = in_sizes[1] / 2;             // eidx is (2, n_edges)
    int n_nodes = in_sizes[0] / 32;            // input is (n_nodes, 32)
    const int* sidx = eidx;
    const int* tidx = eidx + n_edges;

    int K = (n_nodes + SPAN - 1) >> SPAN_SHIFT;   // 782 for 100K nodes

    // Workspace: recs[E int2] | bcnt[KMAX] | bcur0[KMAX] | bbase[KMAX+1]
    size_t need = (size_t)n_edges * 8 + (3 * KMAX + 1) * 4;

    if (ws_size >= need && K <= KMAX) {
        int2* recs  = (int2*)d_ws;
        int*  bcnt  = (int*)(recs + n_edges);
        int*  bcur0 = bcnt + KMAX;
        int*  bbase = bcur0 + KMAX;

        hipMemsetAsync(bcnt, 0, 2 * KMAX * sizeof(int), stream);  // bcnt + bcur0

        bhist_kernel    <<<1024, NB,   0, stream>>>(tidx, bcnt, n_edges);
        bscan_kernel    <<<1,    KMAX, 0, stream>>>(bcnt, bbase, K);
        int pg = (n_edges + PT - 1) / PT;
        partition_kernel<<<pg,   NB,   0, stream>>>(sidx, tidx, enorm, esgn,
                                                    bbase, bcur0, recs, n_edges);
        bucket_accum    <<<K,    1024, 0, stream>>>(input, recs, bbase,
                                                    out, n_nodes);
    } else {
        hipMemsetAsync(d_out, 0, (size_t)out_size * sizeof(float), stream);
        size_t threads_total = (size_t)n_edges * 8;
        int grid = (int)((threads_total + NB - 1) / NB);
        graphconv_scatter<<<grid, NB, 0, stream>>>(input, sidx, tidx, enorm, esgn,
                                                   out, n_edges);
    }
}